// Round 5
// baseline (202.679 us; speedup 1.0000x reference)
//
#include <hip/hip_runtime.h>

// MergeLayer: out = sigmoid(relu([z[e0]; z[e1]] @ W1 + b1) @ W2 + b2)
// Factored: g = z @ Wcat (+b1 on gi half)  -- node-level GEMM via bf16 MFMA
//           out[k] = sigmoid(dot(relu(gi[e0]+gj[e1]), W2) + b2)  -- edge gather
//
// Edge phase gathers 4 random 128B lines/edge from L2-cold tables -> line-miss
// bound. Fix: counting-sort edges by source node (avg degree 12), process
// contiguous sorted chunks per block -> gi lines are reused via intra-
// instruction coalescing + L1, cutting line-misses ~45%.
//
// ws: gi(12.8M) | gj(12.8M) | Wt(64K) | sorted int4(9.6M) | counts | pref |
//     cursor | bsum | boff

#define DD 128
#define NBINS 50176        // 196*256 >= n_nodes
#define SORT_BLOCKS 196

typedef __attribute__((ext_vector_type(8))) short short8;
typedef __attribute__((ext_vector_type(4))) float floatx4;

static __device__ __forceinline__ unsigned short f2bf(float f) {
  unsigned int u = __builtin_bit_cast(unsigned int, f);
  u += 0x7fffu + ((u >> 16) & 1u);   // round-to-nearest-even
  return (unsigned short)(u >> 16);
}
static __device__ __forceinline__ float bflo(unsigned int u) {
  return __builtin_bit_cast(float, u << 16);
}
static __device__ __forceinline__ float bfhi(unsigned int u) {
  return __builtin_bit_cast(float, u & 0xffff0000u);
}

// ---------- prelude: Wt[c][k] = Wcat[k][c] as bf16 ---------------------------
__global__ __launch_bounds__(256) void wt_build(
    const float* __restrict__ W1, unsigned short* __restrict__ Wt) {
  const int g = blockIdx.x * 256 + threadIdx.x;  // 8192 threads total
  const int c = g >> 5;
  const int kq = (g & 31) * 4;
  const float* src = (c < 128) ? (W1 + c) : (W1 + 128 * 128 + (c - 128));
  ushort4 o;
  o.x = f2bf(src[(size_t)(kq + 0) * 128]);
  o.y = f2bf(src[(size_t)(kq + 1) * 128]);
  o.z = f2bf(src[(size_t)(kq + 2) * 128]);
  o.w = f2bf(src[(size_t)(kq + 3) * 128]);
  *(ushort4*)&Wt[c * 128 + kq] = o;
}

// ---------- node GEMM via mfma_f32_16x16x32_bf16 (A=W, B=z) ------------------
__global__ __launch_bounds__(256) void node_mfma(
    const float* __restrict__ z, const unsigned short* __restrict__ Wt,
    const float* __restrict__ b1, unsigned short* __restrict__ gi,
    unsigned short* __restrict__ gj, int n_nodes) {
  __shared__ unsigned short zb[64 * 136];
  const int tid = threadIdx.x;
  const int nb = blockIdx.x * 64;

#pragma unroll
  for (int i = 0; i < 8; ++i) {
    int q = tid + i * 256;
    int nl = q >> 5;
    int node = nb + nl; if (node >= n_nodes) node = n_nodes - 1;
    float4 v = ((const float4*)z)[(size_t)node * 32 + (q & 31)];
    ushort4 o;
    o.x = f2bf(v.x); o.y = f2bf(v.y); o.z = f2bf(v.z); o.w = f2bf(v.w);
    *(ushort4*)&zb[nl * 136 + (q & 31) * 4] = o;
  }

  const int w = tid >> 6, lane = tid & 63;
  const int l15 = lane & 15, quad = lane >> 4;

  short8 a[4][4];
#pragma unroll
  for (int tt = 0; tt < 4; ++tt) {
    const unsigned short* wrow =
        Wt + (size_t)((w * 4 + tt) * 16 + l15) * 128 + quad * 8;
#pragma unroll
    for (int s = 0; s < 4; ++s) a[tt][s] = *(const short8*)(wrow + s * 32);
  }

  floatx4 acc[4][4];
#pragma unroll
  for (int tt = 0; tt < 4; ++tt) {
    floatx4 bias = {0.f, 0.f, 0.f, 0.f};
    if (w < 2) {
      float4 b4 = *(const float4*)&b1[(w * 4 + tt) * 16 + quad * 4];
      bias[0] = b4.x; bias[1] = b4.y; bias[2] = b4.z; bias[3] = b4.w;
    }
#pragma unroll
    for (int nt = 0; nt < 4; ++nt) acc[tt][nt] = bias;
  }

  __syncthreads();

#pragma unroll
  for (int nt = 0; nt < 4; ++nt) {
    short8 bz[4];
#pragma unroll
    for (int s = 0; s < 4; ++s)
      bz[s] = *(const short8*)&zb[(nt * 16 + l15) * 136 + s * 32 + quad * 8];
#pragma unroll
    for (int tt = 0; tt < 4; ++tt)
#pragma unroll
      for (int s = 0; s < 4; ++s)
        acc[tt][nt] =
            __builtin_amdgcn_mfma_f32_16x16x32_bf16(a[tt][s], bz[s], acc[tt][nt], 0, 0, 0);
  }

  unsigned short* base = (w < 2) ? gi : gj;
  const int cbase = w * 64 - ((w < 2) ? 0 : 128);
#pragma unroll
  for (int nt = 0; nt < 4; ++nt) {
    const int node = nb + nt * 16 + l15;
    if (node < n_nodes) {
#pragma unroll
      for (int tt = 0; tt < 4; ++tt) {
        const int c = cbase + tt * 16 + quad * 4;
        ushort4 o;
        o.x = f2bf(acc[tt][nt][0]); o.y = f2bf(acc[tt][nt][1]);
        o.z = f2bf(acc[tt][nt][2]); o.w = f2bf(acc[tt][nt][3]);
        *(ushort4*)&base[(size_t)node * 128 + c] = o;
      }
    }
  }
}

// ---------- counting sort of edges by source node ----------------------------
__global__ __launch_bounds__(256) void k_zero(int* __restrict__ counts) {
  counts[blockIdx.x * 256 + threadIdx.x] = 0;
}

__global__ __launch_bounds__(256) void k_hist(
    const int* __restrict__ e, int* __restrict__ counts, int E) {
  int t = blockIdx.x * 256 + threadIdx.x;
  if (t < E) atomicAdd(&counts[e[t]], 1);
}

__global__ __launch_bounds__(256) void k_scan1(
    const int* __restrict__ counts, int* __restrict__ pref,
    int* __restrict__ bsum) {
  __shared__ int s[256];
  const int t = threadIdx.x;
  const int g = blockIdx.x * 256 + t;
  int v = counts[g];
  s[t] = v;
  __syncthreads();
#pragma unroll
  for (int off = 1; off < 256; off <<= 1) {
    int x = 0;
    if (t >= off) x = s[t - off];
    __syncthreads();
    if (t >= off) s[t] += x;
    __syncthreads();
  }
  pref[g] = s[t] - v;                 // exclusive within block
  if (t == 255) bsum[blockIdx.x] = s[255];
}

__global__ __launch_bounds__(256) void k_scan2(
    const int* __restrict__ bsum, int* __restrict__ boff) {
  __shared__ int s[256];
  const int t = threadIdx.x;
  int v = (t < SORT_BLOCKS) ? bsum[t] : 0;
  s[t] = v;
  __syncthreads();
#pragma unroll
  for (int off = 1; off < 256; off <<= 1) {
    int x = 0;
    if (t >= off) x = s[t - off];
    __syncthreads();
    if (t >= off) s[t] += x;
    __syncthreads();
  }
  if (t < SORT_BLOCKS) boff[t] = s[t] - v;  // exclusive
}

__global__ __launch_bounds__(256) void k_cursor(
    const int* __restrict__ pref, const int* __restrict__ boff,
    int* __restrict__ cursor) {
  const int g = blockIdx.x * 256 + threadIdx.x;
  cursor[g] = pref[g] + boff[g >> 8];
}

__global__ __launch_bounds__(256) void k_scatter(
    const int* __restrict__ e, int* __restrict__ cursor,
    int4* __restrict__ sorted, int E) {
  int t = blockIdx.x * 256 + threadIdx.x;
  if (t < E) {
    int i = e[t], j = e[E + t];
    int pos = atomicAdd(&cursor[i], 1);
    sorted[pos] = make_int4(i, j, t, 0);
  }
}

// ---------- edge phase: sorted contiguous chunks, 8 lanes per edge -----------
static __device__ __forceinline__ float dot8(uint4 a, uint4 b, float4 w0, float4 w1) {
  float s;
  s = fmaxf(bflo(a.x) + bflo(b.x), 0.f) * w0.x;
  s = fmaf(fmaxf(bfhi(a.x) + bfhi(b.x), 0.f), w0.y, s);
  s = fmaf(fmaxf(bflo(a.y) + bflo(b.y), 0.f), w0.z, s);
  s = fmaf(fmaxf(bfhi(a.y) + bfhi(b.y), 0.f), w0.w, s);
  s = fmaf(fmaxf(bflo(a.z) + bflo(b.z), 0.f), w1.x, s);
  s = fmaf(fmaxf(bfhi(a.z) + bfhi(b.z), 0.f), w1.y, s);
  s = fmaf(fmaxf(bflo(a.w) + bflo(b.w), 0.f), w1.z, s);
  s = fmaf(fmaxf(bfhi(a.w) + bfhi(b.w), 0.f), w1.w, s);
  return s;
}

__global__ __launch_bounds__(256) void edge_mlp_sorted(
    const int4* __restrict__ sorted, const unsigned short* __restrict__ gi,
    const unsigned short* __restrict__ gj, const float* __restrict__ W2,
    const float* __restrict__ b2, float* __restrict__ out, int E, int chunk) {
  const int p = threadIdx.x & 7;
  const float4* wv = (const float4*)W2;
  const float4 w0 = wv[p * 2],      w1 = wv[p * 2 + 1];
  const float4 w2 = wv[16 + p * 2], w3 = wv[16 + p * 2 + 1];
  const float bias2 = b2[0];

  const int start = blockIdx.x * chunk;
  const int end   = min(start + chunk, E);
  // contiguous chunk: this block's edges share a narrow source-node range ->
  // gi lines coalesce within instructions and stay L1-hot across iterations.
  for (int k = start + (threadIdx.x >> 3); k < end; k += 32) {
    const int4 s = sorted[k];
    const uint4* pi = (const uint4*)(gi + (size_t)s.x * 128);
    const uint4* pj = (const uint4*)(gj + (size_t)s.y * 128);
    uint4 a0 = pi[p], a1 = pi[8 + p];
    uint4 c0 = pj[p], c1 = pj[8 + p];
    float acc = dot8(a0, c0, w0, w1) + dot8(a1, c1, w2, w3);
    acc += __shfl_xor(acc, 1);
    acc += __shfl_xor(acc, 2);
    acc += __shfl_xor(acc, 4);
    if (p == 0) {
      float x = acc + bias2;
      out[s.z] = 1.f / (1.f + __expf(-x));
    }
  }
}

// ---------- fallback (workspace too small): wave per edge ---------------------
__global__ __launch_bounds__(256) void edge_direct(
    const int* __restrict__ e, const float* __restrict__ z,
    const float* __restrict__ W1, const float* __restrict__ b1,
    const float* __restrict__ W2, const float* __restrict__ b2,
    float* __restrict__ out, int E) {
  const int lane = threadIdx.x & 63;
  const int edge = (int)((blockIdx.x * 256u + threadIdx.x) >> 6);
  if (edge >= E) return;
  const int i = e[edge], j = e[E + edge];
  const float* zi = z + (size_t)i * 128;
  const float* zj = z + (size_t)j * 128;
  const int c0 = lane * 2;
  float h0 = b1[c0], h1 = b1[c0 + 1];
  for (int k = 0; k < 128; ++k) {
    float a = zi[k], b = zj[k];
    float2 wt = *(const float2*)&W1[(size_t)k * 128 + c0];
    float2 wb = *(const float2*)&W1[(size_t)(128 + k) * 128 + c0];
    h0 = fmaf(a, wt.x, h0); h1 = fmaf(a, wt.y, h1);
    h0 = fmaf(b, wb.x, h0); h1 = fmaf(b, wb.y, h1);
  }
  float s = fmaxf(h0, 0.f) * W2[c0] + fmaxf(h1, 0.f) * W2[c0 + 1];
#pragma unroll
  for (int off = 1; off < 64; off <<= 1) s += __shfl_xor(s, off);
  if (lane == 0) out[edge] = 1.f / (1.f + __expf(-(s + b2[0])));
}

extern "C" void kernel_launch(void* const* d_in, const int* in_sizes, int n_in,
                              void* d_out, int out_size, void* d_ws, size_t ws_size,
                              hipStream_t stream) {
  const float* z  = (const float*)d_in[0];
  const int*   e  = (const int*)d_in[1];
  const float* W1 = (const float*)d_in[2];
  const float* b1 = (const float*)d_in[3];
  const float* W2 = (const float*)d_in[4];
  const float* b2 = (const float*)d_in[5];
  float* out = (float*)d_out;
  const int n_nodes = in_sizes[0] / DD;  // 50000
  const int E = in_sizes[1] / 2;         // 600000

  const size_t g_bytes  = (size_t)n_nodes * DD * sizeof(unsigned short);
  const size_t wt_bytes = 256 * 128 * sizeof(unsigned short);  // 64 KB
  const size_t sort_bytes = (size_t)E * sizeof(int4);
  const size_t bin_bytes  = (size_t)NBINS * sizeof(int);
  const size_t need = 2 * g_bytes + wt_bytes + sort_bytes + 3 * bin_bytes +
                      2 * 256 * sizeof(int) + 256;

  if (ws_size >= need && n_nodes <= NBINS) {
    char* p = (char*)d_ws;
    unsigned short* gi = (unsigned short*)p;        p += g_bytes;
    unsigned short* gj = (unsigned short*)p;        p += g_bytes;
    unsigned short* Wt = (unsigned short*)p;        p += wt_bytes;
    int4* sorted       = (int4*)p;                  p += sort_bytes;
    int* counts        = (int*)p;                   p += bin_bytes;
    int* pref          = (int*)p;                   p += bin_bytes;
    int* cursor        = (int*)p;                   p += bin_bytes;
    int* bsum          = (int*)p;                   p += 256 * sizeof(int);
    int* boff          = (int*)p;

    wt_build<<<32, 256, 0, stream>>>(W1, Wt);
    k_zero<<<SORT_BLOCKS, 256, 0, stream>>>(counts);
    node_mfma<<<(n_nodes + 63) / 64, 256, 0, stream>>>(z, Wt, b1, gi, gj, n_nodes);
    k_hist<<<(E + 255) / 256, 256, 0, stream>>>(e, counts, E);
    k_scan1<<<SORT_BLOCKS, 256, 0, stream>>>(counts, pref, bsum);
    k_scan2<<<1, 256, 0, stream>>>(bsum, boff);
    k_cursor<<<SORT_BLOCKS, 256, 0, stream>>>(pref, boff, cursor);
    k_scatter<<<(E + 255) / 256, 256, 0, stream>>>(e, cursor, sorted, E);

    const int nblk = 2048;
    const int chunk = (E + nblk - 1) / nblk;
    edge_mlp_sorted<<<nblk, 256, 0, stream>>>(sorted, gi, gj, W2, b2, out, E, chunk);
  } else {
    edge_direct<<<(E + 3) / 4, 256, 0, stream>>>(e, z, W1, b1, W2, b2, out, E);
  }
}

// Round 6
// 160.654 us; speedup vs baseline: 1.2616x; 1.2616x over previous
//
#include <hip/hip_runtime.h>

// MergeLayer: out = sigmoid(relu([z[e0]; z[e1]] @ W1 + b1) @ W2 + b2)
// Factored: g = z @ Wcat (+b1 on gi half)  -- node-level GEMM via bf16 MFMA
//           out[k] = sigmoid(dot(relu(gi[e0]+gj[e1]), W2) + b2)  -- edge gather
//
// Edge gather is LLC-random-bound (4 random 128B lines/edge, per-XCD L2 hit
// ~16%). Fix: counting-sort edges by coarse source bucket (i>>6 -> 16KB gi
// slice, L1-resident per edge-block). Sort uses ONLY LDS atomics + a
// hierarchical multi-block scan — r5's global-atomic scatter (45us, 2.5GB
// coherence traffic) is eliminated.
//
// ws: gi(12.8M) | gj(12.8M) | Wt(64K) | sorted uint2(4.8M) | counts | part | bsum

#define DD 128
#define NCHUNK 128      // histogram/scatter chunks
#define NBMAX 1024      // max buckets (n_nodes <= 65536)

typedef __attribute__((ext_vector_type(8))) short short8;
typedef __attribute__((ext_vector_type(4))) float floatx4;

static __device__ __forceinline__ unsigned short f2bf(float f) {
  unsigned int u = __builtin_bit_cast(unsigned int, f);
  u += 0x7fffu + ((u >> 16) & 1u);   // round-to-nearest-even
  return (unsigned short)(u >> 16);
}
static __device__ __forceinline__ float bflo(unsigned int u) {
  return __builtin_bit_cast(float, u << 16);
}
static __device__ __forceinline__ float bfhi(unsigned int u) {
  return __builtin_bit_cast(float, u & 0xffff0000u);
}

// ---------- prelude: Wt[c][k] = Wcat[k][c] as bf16 ---------------------------
__global__ __launch_bounds__(256) void wt_build(
    const float* __restrict__ W1, unsigned short* __restrict__ Wt) {
  const int g = blockIdx.x * 256 + threadIdx.x;  // 8192 threads total
  const int c = g >> 5;
  const int kq = (g & 31) * 4;
  const float* src = (c < 128) ? (W1 + c) : (W1 + 128 * 128 + (c - 128));
  ushort4 o;
  o.x = f2bf(src[(size_t)(kq + 0) * 128]);
  o.y = f2bf(src[(size_t)(kq + 1) * 128]);
  o.z = f2bf(src[(size_t)(kq + 2) * 128]);
  o.w = f2bf(src[(size_t)(kq + 3) * 128]);
  *(ushort4*)&Wt[c * 128 + kq] = o;
}

// ---------- node GEMM via mfma_f32_16x16x32_bf16 (A=W, B=z) ------------------
__global__ __launch_bounds__(256) void node_mfma(
    const float* __restrict__ z, const unsigned short* __restrict__ Wt,
    const float* __restrict__ b1, unsigned short* __restrict__ gi,
    unsigned short* __restrict__ gj, int n_nodes) {
  __shared__ unsigned short zb[64 * 136];
  const int tid = threadIdx.x;
  const int nb = blockIdx.x * 64;

#pragma unroll
  for (int i = 0; i < 8; ++i) {
    int q = tid + i * 256;
    int nl = q >> 5;
    int node = nb + nl; if (node >= n_nodes) node = n_nodes - 1;
    float4 v = ((const float4*)z)[(size_t)node * 32 + (q & 31)];
    ushort4 o;
    o.x = f2bf(v.x); o.y = f2bf(v.y); o.z = f2bf(v.z); o.w = f2bf(v.w);
    *(ushort4*)&zb[nl * 136 + (q & 31) * 4] = o;
  }

  const int w = tid >> 6, lane = tid & 63;
  const int l15 = lane & 15, quad = lane >> 4;

  short8 a[4][4];
#pragma unroll
  for (int tt = 0; tt < 4; ++tt) {
    const unsigned short* wrow =
        Wt + (size_t)((w * 4 + tt) * 16 + l15) * 128 + quad * 8;
#pragma unroll
    for (int s = 0; s < 4; ++s) a[tt][s] = *(const short8*)(wrow + s * 32);
  }

  floatx4 acc[4][4];
#pragma unroll
  for (int tt = 0; tt < 4; ++tt) {
    floatx4 bias = {0.f, 0.f, 0.f, 0.f};
    if (w < 2) {
      float4 b4 = *(const float4*)&b1[(w * 4 + tt) * 16 + quad * 4];
      bias[0] = b4.x; bias[1] = b4.y; bias[2] = b4.z; bias[3] = b4.w;
    }
#pragma unroll
    for (int nt = 0; nt < 4; ++nt) acc[tt][nt] = bias;
  }

  __syncthreads();

#pragma unroll
  for (int nt = 0; nt < 4; ++nt) {
    short8 bz[4];
#pragma unroll
    for (int s = 0; s < 4; ++s)
      bz[s] = *(const short8*)&zb[(nt * 16 + l15) * 136 + s * 32 + quad * 8];
#pragma unroll
    for (int tt = 0; tt < 4; ++tt)
#pragma unroll
      for (int s = 0; s < 4; ++s)
        acc[tt][nt] =
            __builtin_amdgcn_mfma_f32_16x16x32_bf16(a[tt][s], bz[s], acc[tt][nt], 0, 0, 0);
  }

  unsigned short* base = (w < 2) ? gi : gj;
  const int cbase = w * 64 - ((w < 2) ? 0 : 128);
#pragma unroll
  for (int nt = 0; nt < 4; ++nt) {
    const int node = nb + nt * 16 + l15;
    if (node < n_nodes) {
#pragma unroll
      for (int tt = 0; tt < 4; ++tt) {
        const int c = cbase + tt * 16 + quad * 4;
        ushort4 o;
        o.x = f2bf(acc[tt][nt][0]); o.y = f2bf(acc[tt][nt][1]);
        o.z = f2bf(acc[tt][nt][2]); o.w = f2bf(acc[tt][nt][3]);
        *(ushort4*)&base[(size_t)node * 128 + c] = o;
      }
    }
  }
}

// ---------- bucket sort by i>>6: LDS histograms, hierarchical scan -----------
__global__ __launch_bounds__(256) void ehist(
    const int* __restrict__ e, int* __restrict__ counts, int E, int NB, int chunk) {
  __shared__ int h[NBMAX];
  const int c = blockIdx.x;
  for (int b = threadIdx.x; b < NB; b += 256) h[b] = 0;
  __syncthreads();
  const int start = c * chunk, end = min(start + chunk, E);
  for (int t = start + threadIdx.x; t < end; t += 256)
    atomicAdd(&h[((unsigned)e[t]) >> 6], 1);
  __syncthreads();
  for (int b = threadIdx.x; b < NB; b += 256)
    counts[b * NCHUNK + c] = h[b];
}

__global__ __launch_bounds__(256) void scanA(
    const int* __restrict__ counts, int* __restrict__ part,
    int* __restrict__ bsum, int M) {
  __shared__ int s[256];
  const int t = threadIdx.x;
  const int g = blockIdx.x * 256 + t;
  int v = (g < M) ? counts[g] : 0;
  s[t] = v;
  __syncthreads();
#pragma unroll
  for (int off = 1; off < 256; off <<= 1) {
    int x = 0;
    if (t >= off) x = s[t - off];
    __syncthreads();
    if (t >= off) s[t] += x;
    __syncthreads();
  }
  if (g < M) part[g] = s[t] - v;               // exclusive within block
  if (t == 255) bsum[blockIdx.x] = s[255];
}

__global__ __launch_bounds__(512) void scanB(int* __restrict__ bsum, int nA) {
  __shared__ int s[512];
  const int t = threadIdx.x;
  int v = (t < nA) ? bsum[t] : 0;
  s[t] = v;
  __syncthreads();
#pragma unroll
  for (int off = 1; off < 512; off <<= 1) {
    int x = 0;
    if (t >= off) x = s[t - off];
    __syncthreads();
    if (t >= off) s[t] += x;
    __syncthreads();
  }
  if (t < nA) bsum[t] = s[t] - v;              // exclusive
}

__global__ __launch_bounds__(256) void escatter(
    const int* __restrict__ e, const int* __restrict__ part,
    const int* __restrict__ bsum, uint2* __restrict__ sorted,
    int E, int NB, int chunk) {
  __shared__ int cur[NBMAX];
  const int c = blockIdx.x;
  for (int b = threadIdx.x; b < NB; b += 256) {
    const int idx = b * NCHUNK + c;
    cur[b] = part[idx] + bsum[idx >> 8];
  }
  __syncthreads();
  const int start = c * chunk, end = min(start + chunk, E);
  for (int t = start + threadIdx.x; t < end; t += 256) {
    const unsigned i = (unsigned)e[t];
    const unsigned j = (unsigned)e[E + t];
    const int pos = atomicAdd(&cur[i >> 6], 1);    // LDS atomic only
    sorted[pos] = make_uint2((j << 16) | i, (unsigned)t);
  }
}

// ---------- edge phase: sorted contiguous chunks, 8 lanes per edge -----------
static __device__ __forceinline__ float dot8(uint4 a, uint4 b, float4 w0, float4 w1) {
  float s;
  s = fmaxf(bflo(a.x) + bflo(b.x), 0.f) * w0.x;
  s = fmaf(fmaxf(bfhi(a.x) + bfhi(b.x), 0.f), w0.y, s);
  s = fmaf(fmaxf(bflo(a.y) + bflo(b.y), 0.f), w0.z, s);
  s = fmaf(fmaxf(bfhi(a.y) + bfhi(b.y), 0.f), w0.w, s);
  s = fmaf(fmaxf(bflo(a.z) + bflo(b.z), 0.f), w1.x, s);
  s = fmaf(fmaxf(bfhi(a.z) + bfhi(b.z), 0.f), w1.y, s);
  s = fmaf(fmaxf(bflo(a.w) + bflo(b.w), 0.f), w1.z, s);
  s = fmaf(fmaxf(bfhi(a.w) + bfhi(b.w), 0.f), w1.w, s);
  return s;
}

__global__ __launch_bounds__(256) void edge_sorted(
    const uint2* __restrict__ sorted, const unsigned short* __restrict__ gi,
    const unsigned short* __restrict__ gj, const float* __restrict__ W2,
    const float* __restrict__ b2, float* __restrict__ out, int E, int chunk) {
  const int p = threadIdx.x & 7;
  const float4* wv = (const float4*)W2;
  const float4 w0 = wv[p * 2],      w1 = wv[p * 2 + 1];
  const float4 w2 = wv[16 + p * 2], w3 = wv[16 + p * 2 + 1];
  const float bias2 = b2[0];

  const int start = blockIdx.x * chunk;
  const int end = min(start + chunk, E);
  // contiguous slice of i-sorted edges: gi working set <= ~16KB (L1-resident)
  for (int k = start + (threadIdx.x >> 3); k < end; k += 32) {
    const uint2 s = sorted[k];
    const int i = s.x & 0xffff;
    const int j = s.x >> 16;
    const uint4* pi = (const uint4*)(gi + (size_t)i * 128);
    const uint4* pj = (const uint4*)(gj + (size_t)j * 128);
    uint4 a0 = pi[p], a1 = pi[8 + p];
    uint4 c0 = pj[p], c1 = pj[8 + p];
    float acc = dot8(a0, c0, w0, w1) + dot8(a1, c1, w2, w3);
    acc += __shfl_xor(acc, 1);
    acc += __shfl_xor(acc, 2);
    acc += __shfl_xor(acc, 4);
    if (p == 0) {
      float x = acc + bias2;
      out[s.y] = 1.f / (1.f + __expf(-x));
    }
  }
}

// ---------- fallback: persistent unsorted (r4 structure) ----------------------
__global__ __launch_bounds__(256) void edge_mlp(
    const int* __restrict__ e, const unsigned short* __restrict__ gi,
    const unsigned short* __restrict__ gj, const float* __restrict__ W2,
    const float* __restrict__ b2, float* __restrict__ out, int E) {
  const int p = threadIdx.x & 7;
  const float4* wv = (const float4*)W2;
  const float4 w0 = wv[p * 2],      w1 = wv[p * 2 + 1];
  const float4 w2 = wv[16 + p * 2], w3 = wv[16 + p * 2 + 1];
  const float bias2 = b2[0];
  const int stride = gridDim.x * 32;
  for (int edge = blockIdx.x * 32 + (threadIdx.x >> 3); edge < E; edge += stride) {
    const int i = e[edge];
    const int j = e[E + edge];
    const uint4* pi = (const uint4*)(gi + (size_t)i * 128);
    const uint4* pj = (const uint4*)(gj + (size_t)j * 128);
    uint4 a0 = pi[p], a1 = pi[8 + p];
    uint4 c0 = pj[p], c1 = pj[8 + p];
    float acc = dot8(a0, c0, w0, w1) + dot8(a1, c1, w2, w3);
    acc += __shfl_xor(acc, 1);
    acc += __shfl_xor(acc, 2);
    acc += __shfl_xor(acc, 4);
    if (p == 0) {
      float x = acc + bias2;
      out[edge] = 1.f / (1.f + __expf(-x));
    }
  }
}

// ---------- fallback (workspace too small): wave per edge ---------------------
__global__ __launch_bounds__(256) void edge_direct(
    const int* __restrict__ e, const float* __restrict__ z,
    const float* __restrict__ W1, const float* __restrict__ b1,
    const float* __restrict__ W2, const float* __restrict__ b2,
    float* __restrict__ out, int E) {
  const int lane = threadIdx.x & 63;
  const int edge = (int)((blockIdx.x * 256u + threadIdx.x) >> 6);
  if (edge >= E) return;
  const int i = e[edge], j = e[E + edge];
  const float* zi = z + (size_t)i * 128;
  const float* zj = z + (size_t)j * 128;
  const int c0 = lane * 2;
  float h0 = b1[c0], h1 = b1[c0 + 1];
  for (int k = 0; k < 128; ++k) {
    float a = zi[k], b = zj[k];
    float2 wt = *(const float2*)&W1[(size_t)k * 128 + c0];
    float2 wb = *(const float2*)&W1[(size_t)(128 + k) * 128 + c0];
    h0 = fmaf(a, wt.x, h0); h1 = fmaf(a, wt.y, h1);
    h0 = fmaf(b, wb.x, h0); h1 = fmaf(b, wb.y, h1);
  }
  float s = fmaxf(h0, 0.f) * W2[c0] + fmaxf(h1, 0.f) * W2[c0 + 1];
#pragma unroll
  for (int off = 1; off < 64; off <<= 1) s += __shfl_xor(s, off);
  if (lane == 0) out[edge] = 1.f / (1.f + __expf(-(s + b2[0])));
}

extern "C" void kernel_launch(void* const* d_in, const int* in_sizes, int n_in,
                              void* d_out, int out_size, void* d_ws, size_t ws_size,
                              hipStream_t stream) {
  const float* z  = (const float*)d_in[0];
  const int*   e  = (const int*)d_in[1];
  const float* W1 = (const float*)d_in[2];
  const float* b1 = (const float*)d_in[3];
  const float* W2 = (const float*)d_in[4];
  const float* b2 = (const float*)d_in[5];
  float* out = (float*)d_out;
  const int n_nodes = in_sizes[0] / DD;  // 50000
  const int E = in_sizes[1] / 2;         // 600000

  const size_t g_bytes  = (size_t)n_nodes * DD * sizeof(unsigned short);
  const size_t wt_bytes = 256 * 128 * sizeof(unsigned short);  // 64 KB
  const int NB = (n_nodes + 63) >> 6;                          // buckets
  const int M  = NB * NCHUNK;
  const int nA = (M + 255) / 256;
  const size_t sort_bytes = (size_t)E * sizeof(uint2);
  const size_t cnt_bytes  = (size_t)M * sizeof(int);
  const size_t need_base  = 2 * g_bytes + wt_bytes;
  const size_t need_sort  = need_base + sort_bytes + 2 * cnt_bytes + 512 * sizeof(int);

  if (ws_size >= need_base) {
    char* p = (char*)d_ws;
    unsigned short* gi = (unsigned short*)p;  p += g_bytes;
    unsigned short* gj = (unsigned short*)p;  p += g_bytes;
    unsigned short* Wt = (unsigned short*)p;  p += wt_bytes;

    wt_build<<<32, 256, 0, stream>>>(W1, Wt);
    node_mfma<<<(n_nodes + 63) / 64, 256, 0, stream>>>(z, Wt, b1, gi, gj, n_nodes);

    if (ws_size >= need_sort && n_nodes <= 65536 && nA <= 512) {
      uint2* sorted = (uint2*)p;  p += sort_bytes;
      int* counts   = (int*)p;    p += cnt_bytes;
      int* part     = (int*)p;    p += cnt_bytes;
      int* bsum     = (int*)p;

      const int chunk = (E + NCHUNK - 1) / NCHUNK;
      ehist<<<NCHUNK, 256, 0, stream>>>(e, counts, E, NB, chunk);
      scanA<<<nA, 256, 0, stream>>>(counts, part, bsum, M);
      scanB<<<1, 512, 0, stream>>>(bsum, nA);
      escatter<<<NCHUNK, 256, 0, stream>>>(e, part, bsum, sorted, E, NB, chunk);

      const int nblk = 2048;
      const int echunk = (E + nblk - 1) / nblk;
      edge_sorted<<<nblk, 256, 0, stream>>>(sorted, gi, gj, W2, b2, out, E, echunk);
    } else {
      edge_mlp<<<2048, 256, 0, stream>>>(e, gi, gj, W2, b2, out, E);
    }
  } else {
    edge_direct<<<(E + 3) / 4, 256, 0, stream>>>(e, z, W1, b1, W2, b2, out, E);
  }
}

// Round 8
// 151.826 us; speedup vs baseline: 1.3349x; 1.0581x over previous
//
#include <hip/hip_runtime.h>

// MergeLayer: out = sigmoid(relu([z[e0]; z[e1]] @ W1 + b1) @ W2 + b2)
// Factored: g = z @ Wcat (+b1 on gi half)  -- node GEMM via bf16 MFMA (~12us,
//           near 51MB memory floor)
//           out = sigmoid(dot(relu(gi[e0]+gj[e1]), W2) + b2)  -- edge gather
//
// Edge gather = 307MB of random 128B lines, ~4.2 TB/s L3-random rate.
// r5/r6 lesson: fine-grained sorts lose to their own scatter cost. This round:
// COARSE 8-bucket partition by j-slice (2MB gj slice, L2-resident per XCD).
// - 8 LDS counters, 1-block scan, scatter into 8 ASCENDING streams (coalesced)
// - edge sweep: persistent blocks stride the sorted array in near-lockstep ->
//   only ~1 slice hot at a time; gi loads non-temporal to protect the slice
// - output written sequentially; final unpermute does random 4B READS from an
//   L2-resident 2.4MB array (cheap) instead of scattered writes.
//
// ws: gi(12.8M) | gj(12.8M) | Wt(64K) | sorted(4.8M) | pos(2.4M) | outs(2.4M)
//     | counts(8K) | part(8K)

#define DD 128
#define NBUCK 8
#define PCHUNK 256          // hist/scatter chunk blocks
#define BSHIFT 13           // bucket = j >> 13  (needs n_nodes <= 65536)

typedef __attribute__((ext_vector_type(8))) short short8;
typedef __attribute__((ext_vector_type(4))) float floatx4;
typedef __attribute__((ext_vector_type(4))) unsigned int uintx4;

static __device__ __forceinline__ unsigned short f2bf(float f) {
  unsigned int u = __builtin_bit_cast(unsigned int, f);
  u += 0x7fffu + ((u >> 16) & 1u);   // round-to-nearest-even
  return (unsigned short)(u >> 16);
}
static __device__ __forceinline__ float bflo(unsigned int u) {
  return __builtin_bit_cast(float, u << 16);
}
static __device__ __forceinline__ float bfhi(unsigned int u) {
  return __builtin_bit_cast(float, u & 0xffff0000u);
}

// ---------- prelude: Wt[c][k] = Wcat[k][c] as bf16 ---------------------------
__global__ __launch_bounds__(256) void wt_build(
    const float* __restrict__ W1, unsigned short* __restrict__ Wt) {
  const int g = blockIdx.x * 256 + threadIdx.x;  // 8192 threads total
  const int c = g >> 5;
  const int kq = (g & 31) * 4;
  const float* src = (c < 128) ? (W1 + c) : (W1 + 128 * 128 + (c - 128));
  ushort4 o;
  o.x = f2bf(src[(size_t)(kq + 0) * 128]);
  o.y = f2bf(src[(size_t)(kq + 1) * 128]);
  o.z = f2bf(src[(size_t)(kq + 2) * 128]);
  o.w = f2bf(src[(size_t)(kq + 3) * 128]);
  *(ushort4*)&Wt[c * 128 + kq] = o;
}

// ---------- node GEMM via mfma_f32_16x16x32_bf16 (A=W, B=z) ------------------
__global__ __launch_bounds__(256) void node_mfma(
    const float* __restrict__ z, const unsigned short* __restrict__ Wt,
    const float* __restrict__ b1, unsigned short* __restrict__ gi,
    unsigned short* __restrict__ gj, int n_nodes) {
  __shared__ unsigned short zb[64 * 136];
  const int tid = threadIdx.x;
  const int nb = blockIdx.x * 64;

#pragma unroll
  for (int i = 0; i < 8; ++i) {
    int q = tid + i * 256;
    int nl = q >> 5;
    int node = nb + nl; if (node >= n_nodes) node = n_nodes - 1;
    float4 v = ((const float4*)z)[(size_t)node * 32 + (q & 31)];
    ushort4 o;
    o.x = f2bf(v.x); o.y = f2bf(v.y); o.z = f2bf(v.z); o.w = f2bf(v.w);
    *(ushort4*)&zb[nl * 136 + (q & 31) * 4] = o;
  }

  const int w = tid >> 6, lane = tid & 63;
  const int l15 = lane & 15, quad = lane >> 4;

  short8 a[4][4];
#pragma unroll
  for (int tt = 0; tt < 4; ++tt) {
    const unsigned short* wrow =
        Wt + (size_t)((w * 4 + tt) * 16 + l15) * 128 + quad * 8;
#pragma unroll
    for (int s = 0; s < 4; ++s) a[tt][s] = *(const short8*)(wrow + s * 32);
  }

  floatx4 acc[4][4];
#pragma unroll
  for (int tt = 0; tt < 4; ++tt) {
    floatx4 bias = {0.f, 0.f, 0.f, 0.f};
    if (w < 2) {
      float4 b4 = *(const float4*)&b1[(w * 4 + tt) * 16 + quad * 4];
      bias[0] = b4.x; bias[1] = b4.y; bias[2] = b4.z; bias[3] = b4.w;
    }
#pragma unroll
    for (int nt = 0; nt < 4; ++nt) acc[tt][nt] = bias;
  }

  __syncthreads();

#pragma unroll
  for (int nt = 0; nt < 4; ++nt) {
    short8 bz[4];
#pragma unroll
    for (int s = 0; s < 4; ++s)
      bz[s] = *(const short8*)&zb[(nt * 16 + l15) * 136 + s * 32 + quad * 8];
#pragma unroll
    for (int tt = 0; tt < 4; ++tt)
#pragma unroll
      for (int s = 0; s < 4; ++s)
        acc[tt][nt] =
            __builtin_amdgcn_mfma_f32_16x16x32_bf16(a[tt][s], bz[s], acc[tt][nt], 0, 0, 0);
  }

  unsigned short* base = (w < 2) ? gi : gj;
  const int cbase = w * 64 - ((w < 2) ? 0 : 128);
#pragma unroll
  for (int nt = 0; nt < 4; ++nt) {
    const int node = nb + nt * 16 + l15;
    if (node < n_nodes) {
#pragma unroll
      for (int tt = 0; tt < 4; ++tt) {
        const int c = cbase + tt * 16 + quad * 4;
        ushort4 o;
        o.x = f2bf(acc[tt][nt][0]); o.y = f2bf(acc[tt][nt][1]);
        o.z = f2bf(acc[tt][nt][2]); o.w = f2bf(acc[tt][nt][3]);
        *(ushort4*)&base[(size_t)node * 128 + c] = o;
      }
    }
  }
}

// ---------- coarse 8-bucket partition by j-slice -----------------------------
__global__ __launch_bounds__(256) void phist(
    const int* __restrict__ e, int* __restrict__ counts, int E, int chunk) {
  __shared__ int h[NBUCK];
  if (threadIdx.x < NBUCK) h[threadIdx.x] = 0;
  __syncthreads();
  const int start = blockIdx.x * chunk, end = min(start + chunk, E);
  for (int t = start + threadIdx.x; t < end; t += 256)
    atomicAdd(&h[((unsigned)e[E + t]) >> BSHIFT], 1);
  __syncthreads();
  if (threadIdx.x < NBUCK)
    counts[threadIdx.x * PCHUNK + blockIdx.x] = h[threadIdx.x];
}

// single block: exclusive scan of counts[NBUCK*PCHUNK = 2048] -> part
__global__ __launch_bounds__(256) void pscan(
    const int* __restrict__ counts, int* __restrict__ part) {
  __shared__ int totals[256];
  const int t = threadIdx.x;
  int pre[8];
  int sum = 0;
#pragma unroll
  for (int k = 0; k < 8; ++k) {
    int v = counts[t * 8 + k];
    pre[k] = sum;
    sum += v;
  }
  totals[t] = sum;
  __syncthreads();
#pragma unroll
  for (int off = 1; off < 256; off <<= 1) {
    int x = 0;
    if (t >= off) x = totals[t - off];
    __syncthreads();
    if (t >= off) totals[t] += x;
    __syncthreads();
  }
  const int boff = (t == 0) ? 0 : totals[t - 1];
#pragma unroll
  for (int k = 0; k < 8; ++k) part[t * 8 + k] = pre[k] + boff;
}

__global__ __launch_bounds__(256) void pscatter(
    const int* __restrict__ e, const int* __restrict__ part,
    uint2* __restrict__ sorted, int* __restrict__ pos, int E, int chunk) {
  __shared__ int cur[NBUCK];
  if (threadIdx.x < NBUCK)
    cur[threadIdx.x] = part[threadIdx.x * PCHUNK + blockIdx.x];
  __syncthreads();
  const int start = blockIdx.x * chunk, end = min(start + chunk, E);
  for (int t = start + threadIdx.x; t < end; t += 256) {
    const unsigned i = (unsigned)e[t];
    const unsigned j = (unsigned)e[E + t];
    const int p = atomicAdd(&cur[j >> BSHIFT], 1);  // 8 ascending streams
    sorted[p] = make_uint2((j << 16) | i, (unsigned)t);
    pos[t] = p;                                      // coalesced
  }
}

// ---------- edge sweep: sorted by j-slice, lockstep stride -------------------
static __device__ __forceinline__ float dot8(uint4 a, uint4 b, float4 w0, float4 w1) {
  float s;
  s = fmaxf(bflo(a.x) + bflo(b.x), 0.f) * w0.x;
  s = fmaf(fmaxf(bfhi(a.x) + bfhi(b.x), 0.f), w0.y, s);
  s = fmaf(fmaxf(bflo(a.y) + bflo(b.y), 0.f), w0.z, s);
  s = fmaf(fmaxf(bfhi(a.y) + bfhi(b.y), 0.f), w0.w, s);
  s = fmaf(fmaxf(bflo(a.z) + bflo(b.z), 0.f), w1.x, s);
  s = fmaf(fmaxf(bfhi(a.z) + bfhi(b.z), 0.f), w1.y, s);
  s = fmaf(fmaxf(bflo(a.w) + bflo(b.w), 0.f), w1.z, s);
  s = fmaf(fmaxf(bfhi(a.w) + bfhi(b.w), 0.f), w1.w, s);
  return s;
}

static __device__ __forceinline__ uint4 nt_load16(const unsigned int* base) {
  uintx4 v = __builtin_nontemporal_load((const uintx4*)base);
  return make_uint4(v.x, v.y, v.z, v.w);
}

__global__ __launch_bounds__(256) void edge_sweep(
    const uint2* __restrict__ sorted, const unsigned short* __restrict__ gi,
    const unsigned short* __restrict__ gj, const float* __restrict__ W2,
    const float* __restrict__ b2, float* __restrict__ outs, int E) {
  const int p = threadIdx.x & 7;
  const float4* wv = (const float4*)W2;
  const float4 w0 = wv[p * 2],      w1 = wv[p * 2 + 1];
  const float4 w2 = wv[16 + p * 2], w3 = wv[16 + p * 2 + 1];
  const float bias2 = b2[0];
  const int stride = gridDim.x * 32;
  // all blocks advance through the j-sorted array together -> at any instant
  // only ~1-2 gj slices (<=4MB) are hot -> gj mostly L2-hit.
  for (int k = blockIdx.x * 32 + (threadIdx.x >> 3); k < E; k += stride) {
    const uint2 s = sorted[k];
    const int i = s.x & 0xffff;
    const int j = s.x >> 16;
    const unsigned int* pi = (const unsigned int*)(gi + (size_t)i * 128);
    const uint4* pj = (const uint4*)(gj + (size_t)j * 128);
    // gi is the random side: non-temporal so it doesn't evict the gj slice
    uint4 a0 = nt_load16(pi + p * 4);
    uint4 a1 = nt_load16(pi + 32 + p * 4);
    uint4 c0 = pj[p], c1 = pj[8 + p];
    float acc = dot8(a0, c0, w0, w1) + dot8(a1, c1, w2, w3);
    acc += __shfl_xor(acc, 1);
    acc += __shfl_xor(acc, 2);
    acc += __shfl_xor(acc, 4);
    if (p == 0) {
      float x = acc + bias2;
      outs[k] = 1.f / (1.f + __expf(-x));   // sequential store
    }
  }
}

// out[t] = outs[pos[t]]: random 4B READS from L2-resident 2.4MB, seq writes
__global__ __launch_bounds__(256) void unpermute(
    const float* __restrict__ outs, const int* __restrict__ pos,
    float* __restrict__ out, int E) {
  const int t = blockIdx.x * 256 + threadIdx.x;
  if (t < E) out[t] = outs[pos[t]];
}

// ---------- fallback: persistent unsorted (r4 structure) ----------------------
__global__ __launch_bounds__(256) void edge_mlp(
    const int* __restrict__ e, const unsigned short* __restrict__ gi,
    const unsigned short* __restrict__ gj, const float* __restrict__ W2,
    const float* __restrict__ b2, float* __restrict__ out, int E) {
  const int p = threadIdx.x & 7;
  const float4* wv = (const float4*)W2;
  const float4 w0 = wv[p * 2],      w1 = wv[p * 2 + 1];
  const float4 w2 = wv[16 + p * 2], w3 = wv[16 + p * 2 + 1];
  const float bias2 = b2[0];
  const int stride = gridDim.x * 32;
  for (int edge = blockIdx.x * 32 + (threadIdx.x >> 3); edge < E; edge += stride) {
    const int i = e[edge];
    const int j = e[E + edge];
    const uint4* pi = (const uint4*)(gi + (size_t)i * 128);
    const uint4* pj = (const uint4*)(gj + (size_t)j * 128);
    uint4 a0 = pi[p], a1 = pi[8 + p];
    uint4 c0 = pj[p], c1 = pj[8 + p];
    float acc = dot8(a0, c0, w0, w1) + dot8(a1, c1, w2, w3);
    acc += __shfl_xor(acc, 1);
    acc += __shfl_xor(acc, 2);
    acc += __shfl_xor(acc, 4);
    if (p == 0) {
      float x = acc + bias2;
      out[edge] = 1.f / (1.f + __expf(-x));
    }
  }
}

// ---------- fallback (workspace too small): wave per edge ---------------------
__global__ __launch_bounds__(256) void edge_direct(
    const int* __restrict__ e, const float* __restrict__ z,
    const float* __restrict__ W1, const float* __restrict__ b1,
    const float* __restrict__ W2, const float* __restrict__ b2,
    float* __restrict__ out, int E) {
  const int lane = threadIdx.x & 63;
  const int edge = (int)((blockIdx.x * 256u + threadIdx.x) >> 6);
  if (edge >= E) return;
  const int i = e[edge], j = e[E + edge];
  const float* zi = z + (size_t)i * 128;
  const float* zj = z + (size_t)j * 128;
  const int c0 = lane * 2;
  float h0 = b1[c0], h1 = b1[c0 + 1];
  for (int k = 0; k < 128; ++k) {
    float a = zi[k], b = zj[k];
    float2 wt = *(const float2*)&W1[(size_t)k * 128 + c0];
    float2 wb = *(const float2*)&W1[(size_t)(128 + k) * 128 + c0];
    h0 = fmaf(a, wt.x, h0); h1 = fmaf(a, wt.y, h1);
    h0 = fmaf(b, wb.x, h0); h1 = fmaf(b, wb.y, h1);
  }
  float s = fmaxf(h0, 0.f) * W2[c0] + fmaxf(h1, 0.f) * W2[c0 + 1];
#pragma unroll
  for (int off = 1; off < 64; off <<= 1) s += __shfl_xor(s, off);
  if (lane == 0) out[edge] = 1.f / (1.f + __expf(-(s + b2[0])));
}

extern "C" void kernel_launch(void* const* d_in, const int* in_sizes, int n_in,
                              void* d_out, int out_size, void* d_ws, size_t ws_size,
                              hipStream_t stream) {
  const float* z  = (const float*)d_in[0];
  const int*   e  = (const int*)d_in[1];
  const float* W1 = (const float*)d_in[2];
  const float* b1 = (const float*)d_in[3];
  const float* W2 = (const float*)d_in[4];
  const float* b2 = (const float*)d_in[5];
  float* out = (float*)d_out;
  const int n_nodes = in_sizes[0] / DD;  // 50000
  const int E = in_sizes[1] / 2;         // 600000

  const size_t g_bytes  = (size_t)n_nodes * DD * sizeof(unsigned short);
  const size_t wt_bytes = 256 * 128 * sizeof(unsigned short);  // 64 KB
  const size_t sort_bytes = (size_t)E * sizeof(uint2);
  const size_t pos_bytes  = (size_t)E * sizeof(int);
  const size_t outs_bytes = (size_t)E * sizeof(float);
  const size_t cnt_bytes  = (size_t)NBUCK * PCHUNK * sizeof(int);
  const size_t need_base = 2 * g_bytes + wt_bytes;
  const size_t need_part =
      need_base + sort_bytes + pos_bytes + outs_bytes + 2 * cnt_bytes;

  if (ws_size >= need_base) {
    char* p = (char*)d_ws;
    unsigned short* gi = (unsigned short*)p;  p += g_bytes;
    unsigned short* gj = (unsigned short*)p;  p += g_bytes;
    unsigned short* Wt = (unsigned short*)p;  p += wt_bytes;

    wt_build<<<32, 256, 0, stream>>>(W1, Wt);
    node_mfma<<<(n_nodes + 63) / 64, 256, 0, stream>>>(z, Wt, b1, gi, gj, n_nodes);

    if (ws_size >= need_part && n_nodes <= 65536) {
      uint2* sorted = (uint2*)p;  p += sort_bytes;
      int* pos      = (int*)p;    p += pos_bytes;
      float* outs   = (float*)p;  p += outs_bytes;
      int* counts   = (int*)p;    p += cnt_bytes;
      int* part     = (int*)p;

      const int chunk = (E + PCHUNK - 1) / PCHUNK;
      phist<<<PCHUNK, 256, 0, stream>>>(e, counts, E, chunk);
      pscan<<<1, 256, 0, stream>>>(counts, part);
      pscatter<<<PCHUNK, 256, 0, stream>>>(e, part, sorted, pos, E, chunk);
      edge_sweep<<<2048, 256, 0, stream>>>(sorted, gi, gj, W2, b2, outs, E);
      unpermute<<<(E + 255) / 256, 256, 0, stream>>>(outs, pos, out, E);
    } else {
      edge_mlp<<<2048, 256, 0, stream>>>(e, gi, gj, W2, b2, out, E);
    }
  } else {
    edge_direct<<<(E + 3) / 4, 256, 0, stream>>>(e, z, W1, b1, W2, b2, out, E);
  }
}

// Round 9
// 135.775 us; speedup vs baseline: 1.4928x; 1.1182x over previous
//
#include <hip/hip_runtime.h>

// MergeLayer: out = sigmoid(relu([z[e0]; z[e1]] @ W1 + b1) @ W2 + b2)
// Factored: g = z @ Wcat (+b1 on gi half)  -- node-level GEMM via bf16 MFMA
//           out[k] = sigmoid(dot(relu(gi[e0]+gj[e1]), W2) + b2)  -- edge gather
// ws layout: gi (N*128 bf16) | gj (N*128 bf16) | Wt (256x128 bf16, 64KB)
//
// BEST CONFIG (r4, 134.3us): persistent grid-stride edge kernel, W2 in
// registers, 8 lanes/edge full-line gathers; node GEMM channel-split across
// waves. Locality restructurings (sort by i: r5/r6; coarse j-partition: r8)
// all NET-REGRESSED: the gather runs at the L3 random-line rate and any
// materialized reorder costs more than it recovers.

#define DD 128

typedef __attribute__((ext_vector_type(8))) short short8;
typedef __attribute__((ext_vector_type(4))) float floatx4;

static __device__ __forceinline__ unsigned short f2bf(float f) {
  unsigned int u = __builtin_bit_cast(unsigned int, f);
  u += 0x7fffu + ((u >> 16) & 1u);   // round-to-nearest-even
  return (unsigned short)(u >> 16);
}
static __device__ __forceinline__ float bflo(unsigned int u) {
  return __builtin_bit_cast(float, u << 16);
}
static __device__ __forceinline__ float bfhi(unsigned int u) {
  return __builtin_bit_cast(float, u & 0xffff0000u);
}

// ---------- prelude: Wt[c][k] = Wcat[k][c] as bf16 ---------------------------
// Wcat[k][c] = (c<128) ? W1[k][c] : W1[128+k][c-128];  W1 is [256][128] fp32.
__global__ __launch_bounds__(256) void wt_build(
    const float* __restrict__ W1, unsigned short* __restrict__ Wt) {
  const int g = blockIdx.x * 256 + threadIdx.x;  // 8192 threads total
  const int c = g >> 5;                          // 0..255
  const int kq = (g & 31) * 4;                   // 0..124
  const float* src = (c < 128) ? (W1 + c) : (W1 + 128 * 128 + (c - 128));
  ushort4 o;
  o.x = f2bf(src[(size_t)(kq + 0) * 128]);
  o.y = f2bf(src[(size_t)(kq + 1) * 128]);
  o.z = f2bf(src[(size_t)(kq + 2) * 128]);
  o.w = f2bf(src[(size_t)(kq + 3) * 128]);
  *(ushort4*)&Wt[c * 128 + kq] = o;
}

// ---------- node GEMM via mfma_f32_16x16x32_bf16 (A=W, B=z) ------------------
// Block: 256 threads = 4 waves, 64 nodes (4 node-tiles). Wave w owns channel
// tiles t = 4w..4w+3 (64 channels) for ALL 4 node-tiles.
__global__ __launch_bounds__(256) void node_mfma(
    const float* __restrict__ z, const unsigned short* __restrict__ Wt,
    const float* __restrict__ b1, unsigned short* __restrict__ gi,
    unsigned short* __restrict__ gj, int n_nodes) {
  __shared__ unsigned short zb[64 * 136];  // 17.4 KB; row stride 136
  const int tid = threadIdx.x;
  const int nb = blockIdx.x * 64;

  // stage z tile -> bf16 LDS (coalesced float4 reads; 8 per thread)
#pragma unroll
  for (int i = 0; i < 8; ++i) {
    int q = tid + i * 256;            // 2048 float4 = 64 nodes x 32
    int nl = q >> 5;
    int node = nb + nl; if (node >= n_nodes) node = n_nodes - 1;
    float4 v = ((const float4*)z)[(size_t)node * 32 + (q & 31)];
    ushort4 o;
    o.x = f2bf(v.x); o.y = f2bf(v.y); o.z = f2bf(v.z); o.w = f2bf(v.w);
    *(ushort4*)&zb[nl * 136 + (q & 31) * 4] = o;
  }

  const int w = tid >> 6, lane = tid & 63;
  const int l15 = lane & 15, quad = lane >> 4;

  // A fragments (W): A[m=lane&15][k=quad*8+j]; t_global = w*4+tt
  short8 a[4][4];
#pragma unroll
  for (int tt = 0; tt < 4; ++tt) {
    const unsigned short* wrow =
        Wt + (size_t)((w * 4 + tt) * 16 + l15) * 128 + quad * 8;
#pragma unroll
    for (int s = 0; s < 4; ++s) a[tt][s] = *(const short8*)(wrow + s * 32);
  }

  floatx4 acc[4][4];  // [tt][nt]
#pragma unroll
  for (int tt = 0; tt < 4; ++tt) {
    floatx4 bias = {0.f, 0.f, 0.f, 0.f};
    if (w < 2) {  // gi half: b1 folded; channel = (w*4+tt)*16 + quad*4 + r
      float4 b4 = *(const float4*)&b1[(w * 4 + tt) * 16 + quad * 4];
      bias[0] = b4.x; bias[1] = b4.y; bias[2] = b4.z; bias[3] = b4.w;
    }
#pragma unroll
    for (int nt = 0; nt < 4; ++nt) acc[tt][nt] = bias;
  }

  __syncthreads();

#pragma unroll
  for (int nt = 0; nt < 4; ++nt) {
    short8 bz[4];  // B[k=quad*8+j][n=lane&15], n -> node
#pragma unroll
    for (int s = 0; s < 4; ++s)
      bz[s] = *(const short8*)&zb[(nt * 16 + l15) * 136 + s * 32 + quad * 8];
#pragma unroll
    for (int tt = 0; tt < 4; ++tt)
#pragma unroll
      for (int s = 0; s < 4; ++s)
        acc[tt][nt] =
            __builtin_amdgcn_mfma_f32_16x16x32_bf16(a[tt][s], bz[s], acc[tt][nt], 0, 0, 0);
  }

  // epilogue: col=lane&15 -> node, row=quad*4+r -> channel (4 consecutive)
  unsigned short* base = (w < 2) ? gi : gj;
  const int cbase = w * 64 - ((w < 2) ? 0 : 128);
#pragma unroll
  for (int nt = 0; nt < 4; ++nt) {
    const int node = nb + nt * 16 + l15;
    if (node < n_nodes) {
#pragma unroll
      for (int tt = 0; tt < 4; ++tt) {
        const int c = cbase + tt * 16 + quad * 4;
        ushort4 o;
        o.x = f2bf(acc[tt][nt][0]); o.y = f2bf(acc[tt][nt][1]);
        o.z = f2bf(acc[tt][nt][2]); o.w = f2bf(acc[tt][nt][3]);
        *(ushort4*)&base[(size_t)node * 128 + c] = o;
      }
    }
  }
}

// ---------- edge phase: persistent, 8 lanes per edge, W2 in registers ---------
static __device__ __forceinline__ float dot8(uint4 a, uint4 b, float4 w0, float4 w1) {
  float s;
  s = fmaxf(bflo(a.x) + bflo(b.x), 0.f) * w0.x;
  s = fmaf(fmaxf(bfhi(a.x) + bfhi(b.x), 0.f), w0.y, s);
  s = fmaf(fmaxf(bflo(a.y) + bflo(b.y), 0.f), w0.z, s);
  s = fmaf(fmaxf(bfhi(a.y) + bfhi(b.y), 0.f), w0.w, s);
  s = fmaf(fmaxf(bflo(a.z) + bflo(b.z), 0.f), w1.x, s);
  s = fmaf(fmaxf(bfhi(a.z) + bfhi(b.z), 0.f), w1.y, s);
  s = fmaf(fmaxf(bflo(a.w) + bflo(b.w), 0.f), w1.z, s);
  s = fmaf(fmaxf(bfhi(a.w) + bfhi(b.w), 0.f), w1.w, s);
  return s;
}

__global__ __launch_bounds__(256) void edge_mlp(
    const int* __restrict__ e, const unsigned short* __restrict__ gi,
    const unsigned short* __restrict__ gj, const float* __restrict__ W2,
    const float* __restrict__ b2, float* __restrict__ out, int E) {
  const int p = threadIdx.x & 7;
  // W2 chunk for this lane, held in 16 VGPRs (512B table, L2-hot; once/wave)
  const float4* wv = (const float4*)W2;
  const float4 w0 = wv[p * 2],      w1 = wv[p * 2 + 1];
  const float4 w2 = wv[16 + p * 2], w3 = wv[16 + p * 2 + 1];
  const float bias2 = b2[0];

  const int stride = gridDim.x * 32;  // 32 edges per block per iteration
  for (int edge = blockIdx.x * 32 + (threadIdx.x >> 3); edge < E; edge += stride) {
    const int i = e[edge];
    const int j = e[E + edge];
    // 8 lanes x 16B cover each 128B line of the two 256B rows, fully used.
    const uint4* pi = (const uint4*)(gi + (size_t)i * 128);
    const uint4* pj = (const uint4*)(gj + (size_t)j * 128);
    uint4 a0 = pi[p], a1 = pi[8 + p];
    uint4 c0 = pj[p], c1 = pj[8 + p];
    float acc = dot8(a0, c0, w0, w1) + dot8(a1, c1, w2, w3);
    acc += __shfl_xor(acc, 1);
    acc += __shfl_xor(acc, 2);
    acc += __shfl_xor(acc, 4);
    if (p == 0) {
      float x = acc + bias2;
      out[edge] = 1.f / (1.f + __expf(-x));
    }
  }
}

// ---------- fallback (workspace too small): wave per edge ---------------------
__global__ __launch_bounds__(256) void edge_direct(
    const int* __restrict__ e, const float* __restrict__ z,
    const float* __restrict__ W1, const float* __restrict__ b1,
    const float* __restrict__ W2, const float* __restrict__ b2,
    float* __restrict__ out, int E) {
  const int lane = threadIdx.x & 63;
  const int edge = (int)((blockIdx.x * 256u + threadIdx.x) >> 6);
  if (edge >= E) return;
  const int i = e[edge], j = e[E + edge];
  const float* zi = z + (size_t)i * 128;
  const float* zj = z + (size_t)j * 128;
  const int c0 = lane * 2;
  float h0 = b1[c0], h1 = b1[c0 + 1];
  for (int k = 0; k < 128; ++k) {
    float a = zi[k], b = zj[k];
    float2 wt = *(const float2*)&W1[(size_t)k * 128 + c0];
    float2 wb = *(const float2*)&W1[(size_t)(128 + k) * 128 + c0];
    h0 = fmaf(a, wt.x, h0); h1 = fmaf(a, wt.y, h1);
    h0 = fmaf(b, wb.x, h0); h1 = fmaf(b, wb.y, h1);
  }
  float s = fmaxf(h0, 0.f) * W2[c0] + fmaxf(h1, 0.f) * W2[c0 + 1];
#pragma unroll
  for (int off = 1; off < 64; off <<= 1) s += __shfl_xor(s, off);
  if (lane == 0) out[edge] = 1.f / (1.f + __expf(-(s + b2[0])));
}

extern "C" void kernel_launch(void* const* d_in, const int* in_sizes, int n_in,
                              void* d_out, int out_size, void* d_ws, size_t ws_size,
                              hipStream_t stream) {
  const float* z  = (const float*)d_in[0];
  const int*   e  = (const int*)d_in[1];
  const float* W1 = (const float*)d_in[2];
  const float* b1 = (const float*)d_in[3];
  const float* W2 = (const float*)d_in[4];
  const float* b2 = (const float*)d_in[5];
  float* out = (float*)d_out;
  const int n_nodes = in_sizes[0] / DD;  // 50000
  const int E = in_sizes[1] / 2;         // 600000

  const size_t g_bytes  = (size_t)n_nodes * DD * sizeof(unsigned short);
  const size_t wt_bytes = 256 * 128 * sizeof(unsigned short);  // 64 KB
  if (ws_size >= 2 * g_bytes + wt_bytes) {
    unsigned short* gi = (unsigned short*)d_ws;
    unsigned short* gj = (unsigned short*)((char*)d_ws + g_bytes);
    unsigned short* Wt = (unsigned short*)((char*)d_ws + 2 * g_bytes);
    wt_build<<<32, 256, 0, stream>>>(W1, Wt);
    node_mfma<<<(n_nodes + 63) / 64, 256, 0, stream>>>(z, Wt, b1, gi, gj, n_nodes);
    edge_mlp<<<2048, 256, 0, stream>>>(e, gi, gj, W2, b2, out, E);
  } else {
    edge_direct<<<(E + 3) / 4, 256, 0, stream>>>(e, z, W1, b1, W2, b2, out, E);
  }
}